// Round 3
// baseline (106.084 us; speedup 1.0000x reference)
//
#include <hip/hip_runtime.h>

typedef unsigned int u32;
typedef unsigned long long u64;

#define BB 16
#define LL 8192
#define CC 512
#define KK 64
#define COLS 16            // columns per block -> 64B (one full line) per row-segment
#define THREADS 512        // 8 waves
#define RPI 128            // rows per iteration = THREADS/4
#define NITER (LL / RPI)   // 64
#define CAP 256
#define THRESH 2.1f        // survivors/col: mean~146 sigma~12 -> [64,256] w/ ~7 sigma margin

// ---- order-preserving fp32 <-> u32 key transforms ----
__device__ __forceinline__ u32 flip_bits(u32 u) {
  return u ^ ((u & 0x80000000u) ? 0xFFFFFFFFu : 0x80000000u);
}
__device__ __forceinline__ u32 unflip_bits(u32 f) {
  return (f & 0x80000000u) ? (f ^ 0x80000000u) : ~f;
}
__device__ __forceinline__ u64 u64max(u64 a, u64 b) { return a > b ? a : b; }
__device__ __forceinline__ u64 u64min(u64 a, u64 b) { return a < b ? a : b; }

// Fused: stream 16 columns x 8192 rows per block (x read exactly once),
// threshold-filter into per-column LDS candidate lists via LDS atomics,
// then per-wave register bitonic sort -> top-64 -> index re-sort -> write.
// Exact slow-path backstop per column (count outside [64,256]).
__global__ __launch_bounds__(THREADS) void kfused(const float* __restrict__ x,
                                                  float* __restrict__ out) {
  __shared__ u64 lists[COLS][CAP];   // 32 KB
  __shared__ u32 cnts[COLS];
  int tid = threadIdx.x;
  int bid = blockIdx.x;
  int b = bid >> 5;                  // / (CC/COLS)
  int c0 = (bid & 31) * COLS;

  for (int i = tid; i < COLS * CAP; i += THREADS) ((u64*)lists)[i] = 0;
  if (tid < COLS) cnts[tid] = 0;
  __syncthreads();

  // ---- streaming phase ----
  int col_grp = tid & 3;             // which float4 within the 16 columns
  int row_t = tid >> 2;              // 0..127
  const float4* base =
      reinterpret_cast<const float4*>(x + (size_t)b * LL * CC + c0) + col_grp;
#pragma unroll 4
  for (int i = 0; i < NITER; ++i) {
    int row = row_t + i * RPI;
    float4 v = base[(size_t)row * (CC / 4)];
    float vs[4] = {v.x, v.y, v.z, v.w};
#pragma unroll
    for (int q = 0; q < 4; ++q) {
      if (vs[q] > THRESH) {
        int col = col_grp * 4 + q;
        u32 pos = atomicAdd(&cnts[col], 1u);   // LDS atomic
        if (pos < CAP)
          lists[col][pos] =
              (((u64)flip_bits(__float_as_uint(vs[q]))) << 32) | (u32)row;
      }
    }
  }
  __syncthreads();

  // ---- per-wave select phase: wave w handles columns 2w, 2w+1 ----
  int lane = tid & 63;
  int w = tid >> 6;
  for (int cc = 0; cc < 2; ++cc) {
    int col = w * 2 + cc;
    const float* colp = x + (size_t)b * LL * CC + (c0 + col);
    u32 total = cnts[col];
    u64 sel;
    if (total >= (u32)KK && total <= (u32)CAP) {
      u64 kk[4];
#pragma unroll
      for (int r = 0; r < 4; ++r) kk[r] = lists[col][r * 64 + lane];
      // bitonic sort 256 keys DESCENDING (registers + shfl)
#pragma unroll
      for (int k = 2; k <= 256; k <<= 1) {
#pragma unroll
        for (int j = k >> 1; j > 0; j >>= 1) {
          if (j >= 64) {
            int rj = j >> 6;
#pragma unroll
            for (int r = 0; r < 4; ++r) {
              int pr = r ^ rj;
              if (pr > r) {
                int e = r * 64 + lane;
                bool descb = ((e & k) == 0);
                u64 a = kk[r], bq = kk[pr];
                u64 mx = u64max(a, bq), mn = u64min(a, bq);
                kk[r] = descb ? mx : mn;
                kk[pr] = descb ? mn : mx;
              }
            }
          } else {
#pragma unroll
            for (int r = 0; r < 4; ++r) {
              u64 other = __shfl_xor(kk[r], j, 64);
              int e = r * 64 + lane;
              bool upper = (lane & j) != 0;
              bool descb = ((e & k) == 0);
              bool keepmax = descb ? !upper : upper;
              kk[r] = keepmax ? u64max(kk[r], other) : u64min(kk[r], other);
            }
          }
        }
      }
      sel = kk[0];  // lane i holds i-th largest key
    } else {
      // exact slow path: 64 rounds of wave-reduce max over keys < prev
      u64 prev = ~0ull;
      sel = 0;
      for (int r = 0; r < KK; ++r) {
        u64 local = 0;
        for (int t = 0; t < LL / 64; ++t) {
          int l = t * 64 + lane;
          float v = colp[(size_t)l * CC];
          u64 key = (((u64)flip_bits(__float_as_uint(v))) << 32) | (u32)l;
          if (key < prev) local = u64max(local, key);
        }
#pragma unroll
        for (int m = 32; m > 0; m >>= 1) local = u64max(local, __shfl_xor(local, m, 64));
        if (lane == r) sel = local;
        prev = local;
      }
    }

    // re-key by (index, value), sort ASCENDING -> original sequence order
    u32 f = (u32)(sel >> 32);
    u32 l = (u32)sel;
    u64 s2 = (((u64)l) << 32) | f;
#pragma unroll
    for (int k = 2; k <= 64; k <<= 1) {
#pragma unroll
      for (int j = k >> 1; j > 0; j >>= 1) {
        u64 other = __shfl_xor(s2, j, 64);
        bool upper = (lane & j) != 0;
        bool ascb = ((lane & k) == 0);
        bool keepmax = ascb ? upper : !upper;
        s2 = keepmax ? u64max(s2, other) : u64min(s2, other);
      }
    }
    out[((size_t)b * KK + lane) * CC + (c0 + col)] =
        __uint_as_float(unflip_bits((u32)s2));
  }
}

extern "C" void kernel_launch(void* const* d_in, const int* in_sizes, int n_in,
                              void* d_out, int out_size, void* d_ws, size_t ws_size,
                              hipStream_t stream) {
  const float* x = (const float*)d_in[0];
  float* out = (float*)d_out;
  kfused<<<BB * (CC / COLS), THREADS, 0, stream>>>(x, out);
}